// Round 9
// baseline (380.010 us; speedup 1.0000x reference)
//
#include <hip/hip_runtime.h>
#include <hip/hip_bf16.h>
#include <stdint.h>

// C = (B,16,16): diag (k,k)=sigmoid(x·Wd[k]+bd[k]); off (i,j)=-softplus(x·Wo[r]+bo[r])
// Permuted GEMM out[b][c], c=i*16+j. M=65536 N=256 K=1024, bf16 MFMA 16x16x32.
// R9: persistent-block streaming. 256 blocks (1/CU) x 512 thr (8 waves).
// Block = 64 cols (g=b>>6) x 1024 rows (y=b&63, 4 panels of 256). B-slice
// (64x1024 bf16 = 128 KB) staged to LDS ONCE (one barrier); main loop has ZERO
// barriers: x->regs (2-deep prefetch) -> pack bf16 -> MFMA with B from LDS
// (1-deep frag prefetch). Swapped operands mfma(W,x): lane holds 4 consecutive
// out cols -> float4 row-major stores, no transpose epilogue.
// Siblings b,b+64,b+128,b+192 share rows AND an XCD (64%8==0) -> x HBM once.

typedef __bf16 bf16x8 __attribute__((ext_vector_type(8)));
typedef float f32x4 __attribute__((ext_vector_type(4)));

#define THREADS 512
#define GSLICE 131072              // per col-group image: 64 cols x 1024 k x 2B
#define WBYTES (GSLICE * 4)

__device__ __forceinline__ unsigned bf_rtne(unsigned u) {
  return (u + 0x7fffu + ((u >> 16) & 1u)) >> 16;
}
__device__ __forceinline__ unsigned pack2(float lo, float hi) {
  return bf_rtne(__float_as_uint(lo)) | (bf_rtne(__float_as_uint(hi)) << 16);
}
__device__ __forceinline__ bf16x8 packfrag(const float4& a, const float4& b) {
  uint4 u;
  u.x = pack2(a.x, a.y); u.y = pack2(a.z, a.w);
  u.z = pack2(b.x, b.y); u.w = pack2(b.z, b.w);
  return *reinterpret_cast<bf16x8*>(&u);
}
__device__ __forceinline__ void gload_lds16(const void* g, void* l) {
  __builtin_amdgcn_global_load_lds(
      (const __attribute__((address_space(1))) unsigned int*)g,
      (__attribute__((address_space(3))) unsigned int*)l, 16, 0, 0);
}

// Image: col c -> group g=c>>6, local cl=c&63.
// byte(cl,k) = g*GSLICE + cl*2048 + ((k*2) ^ ((cl&7)<<4))   (XOR bank swizzle)
__global__ void prep_kernel(const float* __restrict__ Wd, const float* __restrict__ bd,
                            const float* __restrict__ Wo, const float* __restrict__ bo,
                            char* __restrict__ wbuf, float* __restrict__ bias) {
  const int c = blockIdx.x;    // 0..255 output col
  const int t = threadIdx.x;   // 0..255, 4 consecutive k each
  const int i = c >> 4, j = c & 15;
  const float* src;
  float b;
  if (i == j) { src = Wd + i * 1024; b = bd[i]; }
  else { int r = i * 15 + (j < i ? j : j - 1); src = Wo + r * 1024; b = bo[r]; }
  if (t == 0) bias[c] = b;
  const int kk = t * 4;
  const int g = c >> 6, cl = c & 63;
  float4 v = *reinterpret_cast<const float4*>(src + kk);
  uint2 h;
  h.x = pack2(v.x, v.y);
  h.y = pack2(v.z, v.w);
  const unsigned off = (unsigned)(cl * 2048 + ((kk * 2) ^ ((cl & 7) << 4)));
  *reinterpret_cast<uint2*>(wbuf + g * GSLICE + off) = h;
}

__global__ __launch_bounds__(THREADS, 2) void cap_main(
    const float* __restrict__ x, const char* __restrict__ wbuf,
    const float* __restrict__ bias, float* __restrict__ out) {
  __shared__ char smem[GSLICE];

  const int tid = threadIdx.x;
  const int wid = tid >> 6;
  const int lane = tid & 63;
  const int l15 = lane & 15;
  const int l4 = lane >> 4;
  const int b = blockIdx.x;
  const int g = b >> 6;     // col group 0..3
  const int y = b & 63;     // row super-panel

  // ---- stage B slice (128 KB) once ----
  const char* wg = wbuf + g * GSLICE;
#pragma unroll
  for (int i = 0; i < 16; ++i)
    gload_lds16(wg + i * 8192 + tid * 16, smem + i * 8192 + tid * 16);
  __syncthreads();   // the ONLY barrier

  const unsigned swz = (unsigned)((l15 & 7) << 4);
  unsigned cb[4];
#pragma unroll
  for (int n = 0; n < 4; ++n) cb[n] = (unsigned)((n * 16 + l15) * 2048);

#define BREAD(dst, CH)                                                        \
  {                                                                           \
    const unsigned kb = (unsigned)((CH) * 64 + l4 * 16) ^ swz;                \
    _Pragma("unroll") for (int n = 0; n < 4; ++n)                             \
        dst[n] = *reinterpret_cast<const bf16x8*>(smem + cb[n] + kb);         \
  }
#define ALOAD(dst, CH)                                                        \
  {                                                                           \
    const float* p0 = xm0 + (CH) * 32;                                        \
    const float* p1 = xm1 + (CH) * 32;                                        \
    dst[0] = *reinterpret_cast<const float4*>(p0);                            \
    dst[1] = *reinterpret_cast<const float4*>(p0 + 4);                        \
    dst[2] = *reinterpret_cast<const float4*>(p1);                            \
    dst[3] = *reinterpret_cast<const float4*>(p1 + 4);                        \
  }
#define MFMA8(BF, PA)                                                         \
  {                                                                           \
    bf16x8 af0 = packfrag(PA[0], PA[1]);                                      \
    bf16x8 af1 = packfrag(PA[2], PA[3]);                                      \
    _Pragma("unroll") for (int n = 0; n < 4; ++n) {                           \
      acc[0][n] = __builtin_amdgcn_mfma_f32_16x16x32_bf16(BF[n], af0, acc[0][n], 0, 0, 0); \
      acc[1][n] = __builtin_amdgcn_mfma_f32_16x16x32_bf16(BF[n], af1, acc[1][n], 0, 0, 0); \
    }                                                                         \
  }

  for (int p = 0; p < 4; ++p) {
    const size_t r0 = (size_t)y * 1024 + p * 256 + wid * 32 + l15;
    const float* xm0 = x + r0 * 1024 + l4 * 8;
    const float* xm1 = xm0 + 16 * 1024;

    f32x4 acc[2][4];
#pragma unroll
    for (int m = 0; m < 2; ++m)
#pragma unroll
      for (int n = 0; n < 4; ++n) acc[m][n] = (f32x4){0.f, 0.f, 0.f, 0.f};

    float4 pa0[4], pa1[4];
    bf16x8 bfr0[4], bfr1[4];
    ALOAD(pa0, 0);
    ALOAD(pa1, 1);
    BREAD(bfr0, 0);

    for (int ch = 0; ch < 32; ch += 2) {
      // even step: consume pa0/bfr0, prefetch A(ch+2)->pa0, B(ch+1)->bfr1
      {
        bf16x8 af0 = packfrag(pa0[0], pa0[1]);
        bf16x8 af1 = packfrag(pa0[2], pa0[3]);
        const int kA = (ch + 2 < 32) ? ch + 2 : 31;
        ALOAD(pa0, kA);
        BREAD(bfr1, ch + 1);
#pragma unroll
        for (int n = 0; n < 4; ++n) {
          acc[0][n] = __builtin_amdgcn_mfma_f32_16x16x32_bf16(bfr0[n], af0, acc[0][n], 0, 0, 0);
          acc[1][n] = __builtin_amdgcn_mfma_f32_16x16x32_bf16(bfr0[n], af1, acc[1][n], 0, 0, 0);
        }
      }
      // odd step: consume pa1/bfr1, prefetch A(ch+3)->pa1, B(ch+2)->bfr0
      {
        bf16x8 af0 = packfrag(pa1[0], pa1[1]);
        bf16x8 af1 = packfrag(pa1[2], pa1[3]);
        const int kA = (ch + 3 < 32) ? ch + 3 : 31;
        ALOAD(pa1, kA);
        const int kB = (ch + 2 < 32) ? ch + 2 : 31;
        BREAD(bfr0, kB);
#pragma unroll
        for (int n = 0; n < 4; ++n) {
          acc[0][n] = __builtin_amdgcn_mfma_f32_16x16x32_bf16(bfr1[n], af0, acc[0][n], 0, 0, 0);
          acc[1][n] = __builtin_amdgcn_mfma_f32_16x16x32_bf16(bfr1[n], af1, acc[1][n], 0, 0, 0);
        }
      }
    }

    // ---- epilogue: bias + activation + float4 row-major stores (no sync) ----
#pragma unroll
    for (int m = 0; m < 2; ++m) {
#pragma unroll
      for (int n = 0; n < 4; ++n) {
        const int colb = g * 64 + n * 16 + l4 * 4;
        const float4 bb = *reinterpret_cast<const float4*>(bias + colb);
        float4 o;
#pragma unroll
        for (int j2 = 0; j2 < 4; ++j2) {
          const int col = colb + j2;
          const float bvv = (&bb.x)[j2];
          float v = acc[m][n][j2] + bvv;
          float e = __expf(-fabsf(v));
          float sig = (v >= 0.f) ? 1.f / (1.f + e) : e / (1.f + e);
          float sp = fmaxf(v, 0.f) + __logf(1.f + e);
          (&o.x)[j2] = (col % 17 == 0) ? sig : -sp;
        }
        *reinterpret_cast<float4*>(out + (r0 + (size_t)m * 16) * 256 + colb) = o;
      }
    }
  }
#undef BREAD
#undef ALOAD
#undef MFMA8
}

extern "C" void kernel_launch(void* const* d_in, const int* in_sizes, int n_in,
                              void* d_out, int out_size, void* d_ws, size_t ws_size,
                              hipStream_t stream) {
  const float* x = (const float*)d_in[0];
  const float* Wd = (const float*)d_in[1];
  const float* bd = (const float*)d_in[2];
  const float* Wo = (const float*)d_in[3];
  const float* bo = (const float*)d_in[4];
  float* out = (float*)d_out;
  char* wbuf = (char*)d_ws;                  // 512 KiB weight image
  float* bias = (float*)(wbuf + WBYTES);     // 1 KiB bias

  prep_kernel<<<dim3(256), dim3(256), 0, stream>>>(Wd, bd, Wo, bo, wbuf, bias);
  cap_main<<<dim3(256), dim3(THREADS), 0, stream>>>(x, wbuf, bias, out);
}

// Round 12
// 106.628 us; speedup vs baseline: 3.5639x; 3.5639x over previous
//
#include <hip/hip_runtime.h>
#include <hip/hip_bf16.h>
#include <stdint.h>

// C = (B,16,16): diag (k,k)=sigmoid(x·Wd[k]+bd[k]); off (i,j)=-softplus(x·Wo[r]+bo[r])
// Permuted GEMM out[b][c], c=i*16+j. M=65536 N=256 K=1024, bf16 MFMA 16x16x32.
// R12: ALL staging via global_load_lds (1 KB in flight per inst per wave, zero
// VGPR cost -> Little's law satisfied). A staged as fp32 (pre-swizzled global
// source, pack fp32->bf16 after ds_read). 3-slot rotation, per step each wave
// issues 6 gload_lds for chunk t+2 then waits vmcnt(6) (chunk t+1 retired,
// t+2 stays in flight across the raw s_barrier). vmcnt NEVER drains to 0 in
// the loop. BM=64, BK=32, 256 thr (4 waves, 1Mx4N), LDS 72KB -> 2 blocks/CU.

typedef __bf16 bf16x8 __attribute__((ext_vector_type(8)));
typedef float f32x4 __attribute__((ext_vector_type(4)));

#define THREADS 256
#define BM 64
#define KSTEPS 32
#define WIMG 16384                 // per-K-step B image: 256 cols x 32 k x 2B
#define WBYTES (WIMG * KSTEPS)     // 512 KiB

#define ASLOT 8192                 // A slot: 64 rows x 32 k x 4B (fp32), swizzled
#define BBASE 24576                // A slots at 0,8K,16K; B slots at 24K,40K,56K
#define BSLOT 16384
#define SMEM_SZ 73728              // 72 KiB -> 2 blocks/CU

__device__ __forceinline__ unsigned bf_rtne(unsigned u) {
  return (u + 0x7fffu + ((u >> 16) & 1u)) >> 16;
}
__device__ __forceinline__ unsigned pack2(float lo, float hi) {
  return bf_rtne(__float_as_uint(lo)) | (bf_rtne(__float_as_uint(hi)) << 16);
}
__device__ __forceinline__ bf16x8 packfrag(const f32x4& a, const f32x4& b) {
  uint4 u;
  u.x = pack2(a[0], a[1]); u.y = pack2(a[2], a[3]);
  u.z = pack2(b[0], b[1]); u.w = pack2(b[2], b[3]);
  return *reinterpret_cast<bf16x8*>(&u);
}
__device__ __forceinline__ void gload_lds16(const void* g, void* l) {
  __builtin_amdgcn_global_load_lds(
      (const __attribute__((address_space(1))) unsigned int*)g,
      (__attribute__((address_space(3))) unsigned int*)l, 16, 0, 0);
}

// B image per K-step (R4-verified): byte(c,k) = (c*64 + k*2) ^ (((c>>1)&3)<<4)
__global__ void prep_kernel(const float* __restrict__ Wd, const float* __restrict__ bd,
                            const float* __restrict__ Wo, const float* __restrict__ bo,
                            char* __restrict__ wbuf, float* __restrict__ bias) {
  const int c = blockIdx.x;    // 0..255 output col
  const int t = threadIdx.x;   // 0..255, 4 consecutive k each
  const int i = c >> 4, j = c & 15;
  const float* src;
  float b;
  if (i == j) { src = Wd + i * 1024; b = bd[i]; }
  else { int r = i * 15 + (j < i ? j : j - 1); src = Wo + r * 1024; b = bo[r]; }
  if (t == 0) bias[c] = b;
  const int kk = t * 4;
  const int img = kk >> 5, k5 = kk & 31;
  float4 v = *reinterpret_cast<const float4*>(src + kk);
  uint2 h;
  h.x = pack2(v.x, v.y);
  h.y = pack2(v.z, v.w);
  const unsigned off = (unsigned)((c * 64 + k5 * 2) ^ (((c >> 1) & 3) << 4));
  *reinterpret_cast<uint2*>(wbuf + img * WIMG + off) = h;
}

__global__ __launch_bounds__(THREADS, 2) void cap_main(
    const float* __restrict__ x, const char* __restrict__ wbuf,
    const float* __restrict__ bias, float* __restrict__ out) {
  __shared__ char smem[SMEM_SZ];

  const int tid = threadIdx.x;
  const int wid = tid >> 6;      // wave = n-group (0..3), cols wid*64..+63
  const int lane = tid & 63;
  const int l15 = lane & 15;
  const int l4 = lane >> 4;
  const int l7 = lane & 7;
  const int l3 = lane >> 3;      // 0..7

  const size_t blkRow = (size_t)blockIdx.x * BM;

  // ---- A staging (fp32, swizzled): LDS[row][off] with byte = row*128 + (off ^ ((row&7)<<4))
  // gload_lds writes linearly -> pre-swizzle the GLOBAL source address (rule #21).
  // inst v (0..7) covers rows v*8..v*8+7; lane: row = v*8 + l3, floats (l7*4)^(l3<<2).
  const float* asrc0 = x + (blkRow + (size_t)((wid * 2 + 0) * 8 + l3)) * 1024 + ((l7 * 4) ^ (l3 << 2));
  const float* asrc1 = x + (blkRow + (size_t)((wid * 2 + 1) * 8 + l3)) * 1024 + ((l7 * 4) ^ (l3 << 2));
  const unsigned adst0 = (unsigned)((wid * 2 + 0) * 1024 + lane * 16);
  const unsigned adst1 = (unsigned)((wid * 2 + 1) * 1024 + lane * 16);

  // ---- fragment read bases ----
  const unsigned swA = (unsigned)((l15 & 7) << 4);
  const unsigned swB = (unsigned)(((l15 >> 1) & 3) << 4);
  const unsigned bbase = (unsigned)(((wid * 64 + l15) * 64 + l4 * 16) ^ swB);  // + n*1024

  f32x4 acc[4][4];
#pragma unroll
  for (int m = 0; m < 4; ++m)
#pragma unroll
    for (int n = 0; n < 4; ++n) acc[m][n] = (f32x4){0.f, 0.f, 0.f, 0.f};

#define STAGE(CH, ASL, BSL)                                                     \
  {                                                                             \
    gload_lds16(asrc0 + (CH) * 32, smem + (ASL) + adst0);                       \
    gload_lds16(asrc1 + (CH) * 32, smem + (ASL) + adst1);                       \
    const char* wsp = wbuf + (CH) * WIMG;                                       \
    _Pragma("unroll") for (int i = 0; i < 4; ++i)                               \
        gload_lds16(wsp + (wid * 4 + i) * 1024 + lane * 16,                     \
                    smem + (BSL) + (wid * 4 + i) * 1024 + lane * 16);           \
  }

  // ---- prologue: chunk0 -> slot0, chunk1 -> slot1; wait chunk0 only ----
  STAGE(0, 0, BBASE);
  STAGE(1, ASLOT, BBASE + BSLOT);
  asm volatile("s_waitcnt vmcnt(6)\n\ts_barrier" ::: "memory");

  unsigned aR = 0, bR = BBASE;                       // slot of chunk t
  unsigned aI = 2 * ASLOT, bI = BBASE + 2 * BSLOT;   // slot of chunk t+2

  for (int t = 0; t < KSTEPS; ++t) {
    // issue chunk t+2 (6 gload_lds per wave; clamped redundant at tail)
    const int ch = (t + 2 < KSTEPS) ? t + 2 : KSTEPS - 1;
    STAGE(ch, aI, bI);

    // fragments: A fp32 -> pack bf16; B bf16 direct
    const char* Ac = smem + aR;
    const char* Bc = smem + bR;
    bf16x8 af[4], bfr[4];
#pragma unroll
    for (int m = 0; m < 4; ++m) {
      const unsigned rb = (unsigned)((m * 16 + l15) * 128);
      f32x4 u0 = *reinterpret_cast<const f32x4*>(Ac + rb + ((l4 * 32) ^ swA));
      f32x4 u1 = *reinterpret_cast<const f32x4*>(Ac + rb + ((l4 * 32 + 16) ^ swA));
      af[m] = packfrag(u0, u1);
    }
#pragma unroll
    for (int n = 0; n < 4; ++n)
      bfr[n] = *reinterpret_cast<const bf16x8*>(Bc + bbase + n * 1024);

#pragma unroll
    for (int m = 0; m < 4; ++m)
#pragma unroll
      for (int n = 0; n < 4; ++n)
        acc[m][n] = __builtin_amdgcn_mfma_f32_16x16x32_bf16(af[m], bfr[n], acc[m][n], 0, 0, 0);

    // counted wait: retires chunk t+1 (resident for next step); chunk t+2's 6
    // insts stay in flight across the barrier. NEVER vmcnt(0) in the loop.
    asm volatile("s_waitcnt vmcnt(6)\n\ts_barrier" ::: "memory");

    // rotate 3-slot ring
    aR = (aR == 2 * ASLOT) ? 0u : aR + ASLOT;
    aI = (aI == 2 * ASLOT) ? 0u : aI + ASLOT;
    bR = (bR == BBASE + 2 * BSLOT) ? (unsigned)BBASE : bR + BSLOT;
    bI = (bI == BBASE + 2 * BSLOT) ? (unsigned)BBASE : bI + BSLOT;
  }
#undef STAGE

  // drain tail loads before reusing LDS for the epilogue
  asm volatile("s_waitcnt vmcnt(0)" ::: "memory");
  __syncthreads();

  // ---- epilogue (R4-verified): activation -> LDS transpose (1040B pitch) ----
  float bs[4];
#pragma unroll
  for (int n = 0; n < 4; ++n) bs[n] = bias[wid * 64 + n * 16 + l15];

  const int rr2 = tid >> 4;            // 0..15 read-back row
  const int co = (tid & 15) * 16;      // read-back col (floats)
  const char* rdp = smem + rr2 * 1040 + co * 4;

#pragma unroll
  for (int p = 0; p < 4; ++p) {
#pragma unroll
    for (int n = 0; n < 4; ++n) {
      const int col = wid * 64 + n * 16 + l15;
      const bool diag = (col % 17) == 0;
#pragma unroll
      for (int j2 = 0; j2 < 4; ++j2) {
        const int rr = l4 * 4 + j2;
        float v = acc[p][n][j2] + bs[n];
        float e = __expf(-fabsf(v));
        float sig = (v >= 0.f) ? 1.f / (1.f + e) : e / (1.f + e);
        float sp = fmaxf(v, 0.f) + __logf(1.f + e);
        *reinterpret_cast<float*>(smem + rr * 1040 + col * 4) = diag ? sig : -sp;
      }
    }
    __syncthreads();
    float4 o0 = *reinterpret_cast<const float4*>(rdp);
    float4 o1 = *reinterpret_cast<const float4*>(rdp + 16);
    float4 o2 = *reinterpret_cast<const float4*>(rdp + 32);
    float4 o3 = *reinterpret_cast<const float4*>(rdp + 48);
    float* orow = out + (blkRow + (size_t)(p * 16 + rr2)) * 256 + co;
    *reinterpret_cast<float4*>(orow) = o0;
    *reinterpret_cast<float4*>(orow + 4) = o1;
    *reinterpret_cast<float4*>(orow + 8) = o2;
    *reinterpret_cast<float4*>(orow + 12) = o3;
    __syncthreads();
  }
}

extern "C" void kernel_launch(void* const* d_in, const int* in_sizes, int n_in,
                              void* d_out, int out_size, void* d_ws, size_t ws_size,
                              hipStream_t stream) {
  const float* x = (const float*)d_in[0];
  const float* Wd = (const float*)d_in[1];
  const float* bd = (const float*)d_in[2];
  const float* Wo = (const float*)d_in[3];
  const float* bo = (const float*)d_in[4];
  float* out = (float*)d_out;
  char* wbuf = (char*)d_ws;                  // 512 KiB weight image
  float* bias = (float*)(wbuf + WBYTES);     // 1 KiB bias

  prep_kernel<<<dim3(256), dim3(256), 0, stream>>>(Wd, bd, Wo, bo, wbuf, bias);
  cap_main<<<dim3(1024), dim3(THREADS), 0, stream>>>(x, wbuf, bias, out);
}